// Round 1
// 679.221 us; speedup vs baseline: 1.0003x; 1.0003x over previous
//
#include <hip/hip_runtime.h>
#include <hip/hip_bf16.h>
#include <math.h>

// Problem constants
#define B_   16
#define IN_  1024
#define H_   1024
#define DK_  1024
#define D1_  4096
#define LR_  0.01f

typedef float vf4 __attribute__((ext_vector_type(4)));

// ---------------------------------------------------------------------------
// Generic small-N GEMM: out[b*R + r] = sum_k W[r*K + k] * V[b*K + k], b in [0,16)
// One wave per row (4 rows / 256-thread block). V tile staged in LDS.
// K must be a multiple of 256.
// ---------------------------------------------------------------------------
__global__ __launch_bounds__(256) void rowgemm16(
    const float* __restrict__ W, const float* __restrict__ V,
    float* __restrict__ out, int R, int K) {
  __shared__ float vtile[16][256];   // 16 KB
  const int tid  = threadIdx.x;
  const int wave = tid >> 6;
  const int lane = tid & 63;
  const int row  = blockIdx.x * 4 + wave;
  float acc[16];
#pragma unroll
  for (int b = 0; b < 16; ++b) acc[b] = 0.f;
  const float* wrow = W + (size_t)row * K;
  for (int k0 = 0; k0 < K; k0 += 256) {
    __syncthreads();
    // cooperative stage of V[0:16][k0:k0+256] (1024 float4 slots, 256 threads)
#pragma unroll
    for (int idx = tid; idx < 1024; idx += 256) {
      int b = idx >> 6;
      int c = (idx & 63) << 2;
      *(vf4*)&vtile[b][c] = *(const vf4*)(V + (size_t)b * K + k0 + c);
    }
    __syncthreads();
    const int c = lane << 2;
    vf4 w4 = *(const vf4*)(wrow + k0 + c);
#pragma unroll
    for (int b = 0; b < 16; ++b) {
      vf4 v4 = *(const vf4*)&vtile[b][c];
      acc[b] += w4.x * v4.x + w4.y * v4.y + w4.z * v4.z + w4.w * v4.w;
    }
  }
  // wave-level reduction of each of the 16 accumulators
#pragma unroll
  for (int b = 0; b < 16; ++b) {
    float a = acc[b];
#pragma unroll
    for (int off = 32; off; off >>= 1) a += __shfl_down(a, off, 64);
    if (lane == 0) out[(size_t)b * R + row] = a;
  }
}

// ---------------------------------------------------------------------------
// Exact GELU forward + derivative:  g = x*Phi(x),  gp = Phi(x) + x*phi(x)
// n = 16*4096
// ---------------------------------------------------------------------------
__global__ __launch_bounds__(256) void gelu_kernel(
    const float* __restrict__ z, float* __restrict__ g, float* __restrict__ gp) {
  const int idx = blockIdx.x * 256 + threadIdx.x;
  const float x   = z[idx];
  const float cdf = 0.5f * (1.f + erff(x * 0.70710678118654752f));
  g[idx]  = x * cdf;
  gp[idx] = cdf + x * 0.39894228040143268f * expf(-0.5f * x * x);
}

// dh[b][i] = (h[b][i] - v[b][i]) / H    (n = 16*1024)
__global__ __launch_bounds__(256) void dh_kernel(
    const float* __restrict__ h, const float* __restrict__ v, float* __restrict__ dh) {
  const int idx = blockIdx.x * 256 + threadIdx.x;
  dh[idx] = (h[idx] - v[idx]) * (1.0f / 1024.0f);
}

// ---------------------------------------------------------------------------
// dg partials: partial[s][b][j] = sum_{i in chunk s} W1[i][j]*dh[b][i]
// grid = (16 j-tiles, 16 i-chunks of 64 rows), block = 256
// ---------------------------------------------------------------------------
__global__ __launch_bounds__(256) void colgemm_partial(
    const float* __restrict__ W1, const float* __restrict__ dh,
    float* __restrict__ partial) {
  __shared__ float dhs[16][64];
  const int t  = threadIdx.x;
  const int j  = blockIdx.x * 256 + t;
  const int i0 = blockIdx.y * 64;
#pragma unroll
  for (int idx = t; idx < 16 * 64; idx += 256) {
    int b = idx >> 6, c = idx & 63;
    dhs[b][c] = dh[b * 1024 + i0 + c];
  }
  __syncthreads();
  float acc[16];
#pragma unroll
  for (int b = 0; b < 16; ++b) acc[b] = 0.f;
  for (int c = 0; c < 64; ++c) {
    float w = W1[(size_t)(i0 + c) * D1_ + j];   // coalesced across threads
#pragma unroll
    for (int b = 0; b < 16; ++b) acc[b] += w * dhs[b][c];
  }
  const int s = blockIdx.y;
#pragma unroll
  for (int b = 0; b < 16; ++b)
    partial[((size_t)s * 16 + b) * D1_ + j] = acc[b];
}

// dz[b][j] = (sum_s partial[s][b][j]) * gp[b][j]     (n = 16*4096)
__global__ __launch_bounds__(256) void reduce_dz(
    const float* __restrict__ partial, const float* __restrict__ gp,
    float* __restrict__ dz) {
  const int idx = blockIdx.x * 256 + threadIdx.x;
  float s = 0.f;
#pragma unroll
  for (int p = 0; p < 16; ++p) s += partial[(size_t)p * (16 * D1_) + idx];
  dz[idx] = s * gp[idx];
}

// ---------------------------------------------------------------------------
// W0_new[b][i][j] = W0[i][j] - LR * dz[b][i] * kt[b][j]
// One thread per (i, j/4): W0 element read once, 16 PLAIN float4 stores.
// (Round 1 A/B: nontemporal stores removed — suspected uncached 16B-granular
//  write path at ~1 TB/s vs 6.37 TB/s plain-store fill on this device.)
// grid = 4096 blocks * 256 threads = 1M threads (4096 rows x 256 j4)
// ---------------------------------------------------------------------------
__global__ __launch_bounds__(256) void update_w0_kernel(
    const float* __restrict__ W0, const float* __restrict__ dz,
    const float* __restrict__ kt, float* __restrict__ out) {
  const int t = blockIdx.x * 256 + threadIdx.x;
  const int i = t >> 8;           // [0,4096)
  const int j = (t & 255) << 2;   // [0,1024) step 4
  const vf4 w = *(const vf4*)(W0 + ((size_t)i << 10) + j);
#pragma unroll
  for (int b = 0; b < 16; ++b) {
    const float d  = LR_ * dz[(b << 12) + i];                  // wave-uniform
    const vf4   k4 = *(const vf4*)(kt + (b << 10) + j);        // L1-resident
    vf4 o = w - d * k4;
    *(vf4*)(out + ((size_t)b << 22) + ((size_t)i << 10) + j) = o;
  }
}

// ---------------------------------------------------------------------------
// W1_new[b][i][j] = W1[i][j] - LR * dh[b][i] * g[b][j]
// grid = 4096 blocks * 256 threads (1024 rows x 1024 j4)
// ---------------------------------------------------------------------------
__global__ __launch_bounds__(256) void update_w1_kernel(
    const float* __restrict__ W1, const float* __restrict__ dh,
    const float* __restrict__ g, float* __restrict__ out) {
  const int t = blockIdx.x * 256 + threadIdx.x;
  const int i = t >> 10;           // [0,1024)
  const int j = (t & 1023) << 2;   // [0,4096) step 4
  const vf4 w = *(const vf4*)(W1 + ((size_t)i << 12) + j);
#pragma unroll
  for (int b = 0; b < 16; ++b) {
    const float d  = LR_ * dh[(b << 10) + i];                  // wave-uniform
    const vf4   g4 = *(const vf4*)(g + (b << 12) + j);         // L2-resident
    vf4 o = w - d * g4;
    *(vf4*)(out + ((size_t)b << 22) + ((size_t)i << 12) + j) = o;
  }
}

extern "C" void kernel_launch(void* const* d_in, const int* in_sizes, int n_in,
                              void* d_out, int out_size, void* d_ws, size_t ws_size,
                              hipStream_t stream) {
  const float* x_t = (const float*)d_in[0];  // [16,1024]
  const float* W_k = (const float*)d_in[1];  // [1024,1024]
  const float* W_v = (const float*)d_in[2];  // [1024,1024]
  const float* W_o = (const float*)d_in[3];  // [1024,1024]
  const float* W0  = (const float*)d_in[4];  // [4096,1024]
  const float* W1  = (const float*)d_in[5];  // [1024,4096]

  float* out0 = (float*)d_out;               // output [16,1024]
  float* out1 = out0 + 16384;                // W0_new [16,4096,1024]
  float* out2 = out1 + (size_t)16 * 4096 * 1024;  // W1_new [16,1024,4096]

  // workspace layout (floats)
  float* ws      = (float*)d_ws;
  float* kt      = ws;                  // 16*1024
  float* vt      = kt + 16384;          // 16*1024
  float* z       = vt + 16384;          // 16*4096
  float* g       = z + 65536;           // 16*4096
  float* gp      = g + 65536;           // 16*4096
  float* h       = gp + 65536;          // 16*1024
  float* dh      = h + 16384;           // 16*1024
  float* dz      = dh + 16384;          // 16*4096
  float* partial = dz + 65536;          // 16*16*4096

  // projections: k_t = x @ W_k^T, v_t = x @ W_v^T
  rowgemm16<<<256, 256, 0, stream>>>(W_k, x_t, kt, 1024, 1024);
  rowgemm16<<<256, 256, 0, stream>>>(W_v, x_t, vt, 1024, 1024);
  // forward MLP
  rowgemm16<<<1024, 256, 0, stream>>>(W0, kt, z, 4096, 1024);
  gelu_kernel<<<256, 256, 0, stream>>>(z, g, gp);
  rowgemm16<<<256, 256, 0, stream>>>(W1, g, h, 1024, 4096);
  // gradient
  dh_kernel<<<64, 256, 0, stream>>>(h, vt, dh);
  colgemm_partial<<<dim3(16, 16), 256, 0, stream>>>(W1, dh, partial);
  reduce_dz<<<256, 256, 0, stream>>>(partial, gp, dz);
  // output projection: output = h @ W_o^T
  rowgemm16<<<256, 256, 0, stream>>>(W_o, h, out0, 1024, 1024);
  // weight updates (the two big streaming writes)
  update_w0_kernel<<<4096, 256, 0, stream>>>(W0, dz, kt, out1);
  update_w1_kernel<<<4096, 256, 0, stream>>>(W1, dh, g, out2);
}

// Round 2
// 650.382 us; speedup vs baseline: 1.0447x; 1.0443x over previous
//
#include <hip/hip_runtime.h>
#include <hip/hip_bf16.h>
#include <math.h>

// Problem constants
#define B_   16
#define IN_  1024
#define H_   1024
#define DK_  1024
#define D1_  4096
#define LR_  0.01f

typedef float vf4 __attribute__((ext_vector_type(4)));

// ---------------------------------------------------------------------------
// Shared inner loop: wave computes dot(W row, V[b] row) for b in [0,16),
// V tile staged in LDS. K multiple of 256. Result: acc[b] reduced across wave,
// final value for each b lands on lane 0.
// ---------------------------------------------------------------------------
#define ROWGEMM_BODY(WPTR, VPTR, K)                                         \
  __shared__ float vtile[16][256];                                          \
  const int tid  = threadIdx.x;                                             \
  const int wave = tid >> 6;                                                \
  const int lane = tid & 63;                                                \
  float acc[16];                                                            \
  _Pragma("unroll")                                                         \
  for (int b = 0; b < 16; ++b) acc[b] = 0.f;                                \
  for (int k0 = 0; k0 < (K); k0 += 256) {                                   \
    __syncthreads();                                                        \
    _Pragma("unroll")                                                       \
    for (int idx = tid; idx < 1024; idx += 256) {                           \
      int bb = idx >> 6;                                                    \
      int cc = (idx & 63) << 2;                                             \
      *(vf4*)&vtile[bb][cc] = *(const vf4*)((VPTR) + (size_t)bb * (K) + k0 + cc); \
    }                                                                       \
    __syncthreads();                                                        \
    const int c = lane << 2;                                                \
    vf4 w4 = *(const vf4*)((WPTR) + k0 + c);                                \
    _Pragma("unroll")                                                       \
    for (int b = 0; b < 16; ++b) {                                          \
      vf4 v4 = *(const vf4*)&vtile[b][c];                                   \
      acc[b] += w4.x * v4.x + w4.y * v4.y + w4.z * v4.z + w4.w * v4.w;      \
    }                                                                       \
  }                                                                         \
  _Pragma("unroll")                                                         \
  for (int b = 0; b < 16; ++b) {                                            \
    float a = acc[b];                                                       \
    _Pragma("unroll")                                                       \
    for (int off = 32; off; off >>= 1) a += __shfl_down(a, off, 64);        \
    acc[b] = a;                                                             \
  }

// ---------------------------------------------------------------------------
// Plain variant: out[b*R + row] = dot   (used for output projection)
// ---------------------------------------------------------------------------
__global__ __launch_bounds__(256) void rowgemm16(
    const float* __restrict__ W, const float* __restrict__ V,
    float* __restrict__ out, int R, int K) {
  const int row = blockIdx.x * 4 + (threadIdx.x >> 6);
  const float* wrow = W + (size_t)row * K;
  ROWGEMM_BODY(wrow, V, K)
  if (lane == 0) {
#pragma unroll
    for (int b = 0; b < 16; ++b) out[(size_t)b * R + row] = acc[b];
  }
}

// ---------------------------------------------------------------------------
// Fused projections: rows [0,1024) -> kt from W_k, rows [1024,2048) -> vt from W_v
// grid = 512 blocks
// ---------------------------------------------------------------------------
__global__ __launch_bounds__(256) void proj_kernel(
    const float* __restrict__ W_k, const float* __restrict__ W_v,
    const float* __restrict__ x, float* __restrict__ kt, float* __restrict__ vt) {
  const int grow = blockIdx.x * 4 + (threadIdx.x >> 6);
  const int row  = grow & 1023;
  const float* wrow = (grow < 1024 ? W_k : W_v) + (size_t)row * 1024;
  float* out = (grow < 1024) ? kt : vt;
  ROWGEMM_BODY(wrow, x, 1024)
  if (lane == 0) {
#pragma unroll
    for (int b = 0; b < 16; ++b) out[b * 1024 + row] = acc[b];
  }
}

// ---------------------------------------------------------------------------
// z = W0 @ kt with fused exact-GELU epilogue: writes g and gp directly.
// grid = 1024 blocks (rows of 4096)
// ---------------------------------------------------------------------------
__global__ __launch_bounds__(256) void z_gelu_kernel(
    const float* __restrict__ W0, const float* __restrict__ kt,
    float* __restrict__ g, float* __restrict__ gp) {
  const int row = blockIdx.x * 4 + (threadIdx.x >> 6);
  const float* wrow = W0 + (size_t)row * 1024;
  ROWGEMM_BODY(wrow, kt, 1024)
  if (lane == 0) {
#pragma unroll
    for (int b = 0; b < 16; ++b) {
      const float x   = acc[b];
      const float cdf = 0.5f * (1.f + erff(x * 0.70710678118654752f));
      g[b * 4096 + row]  = x * cdf;
      gp[b * 4096 + row] = cdf + x * 0.39894228040143268f * expf(-0.5f * x * x);
    }
  }
}

// ---------------------------------------------------------------------------
// h = W1 @ g with fused dh epilogue: dh = (h - vt)/1024. grid = 256 blocks.
// ---------------------------------------------------------------------------
__global__ __launch_bounds__(256) void h_dh_kernel(
    const float* __restrict__ W1, const float* __restrict__ g,
    const float* __restrict__ vt, float* __restrict__ h, float* __restrict__ dh) {
  const int row = blockIdx.x * 4 + (threadIdx.x >> 6);
  const float* wrow = W1 + (size_t)row * 4096;
  ROWGEMM_BODY(wrow, g, 4096)
  if (lane == 0) {
#pragma unroll
    for (int b = 0; b < 16; ++b) {
      const float hv = acc[b];
      h[b * 1024 + row]  = hv;
      dh[b * 1024 + row] = (hv - vt[b * 1024 + row]) * (1.0f / 1024.0f);
    }
  }
}

// ---------------------------------------------------------------------------
// dg partials: partial[s][b][j] = sum_{i in chunk s} W1[i][j]*dh[b][i]
// grid = (16 j-tiles, 16 i-chunks of 64 rows), block = 256
// ---------------------------------------------------------------------------
__global__ __launch_bounds__(256) void colgemm_partial(
    const float* __restrict__ W1, const float* __restrict__ dh,
    float* __restrict__ partial) {
  __shared__ float dhs[16][64];
  const int t  = threadIdx.x;
  const int j  = blockIdx.x * 256 + t;
  const int i0 = blockIdx.y * 64;
#pragma unroll
  for (int idx = t; idx < 16 * 64; idx += 256) {
    int b = idx >> 6, c = idx & 63;
    dhs[b][c] = dh[b * 1024 + i0 + c];
  }
  __syncthreads();
  float acc[16];
#pragma unroll
  for (int b = 0; b < 16; ++b) acc[b] = 0.f;
  for (int c = 0; c < 64; ++c) {
    float w = W1[(size_t)(i0 + c) * D1_ + j];   // coalesced across threads
#pragma unroll
    for (int b = 0; b < 16; ++b) acc[b] += w * dhs[b][c];
  }
  const int s = blockIdx.y;
#pragma unroll
  for (int b = 0; b < 16; ++b)
    partial[((size_t)s * 16 + b) * D1_ + j] = acc[b];
}

// dz[b][j] = (sum_s partial[s][b][j]) * gp[b][j]     (n = 16*4096)
__global__ __launch_bounds__(256) void reduce_dz(
    const float* __restrict__ partial, const float* __restrict__ gp,
    float* __restrict__ dz) {
  const int idx = blockIdx.x * 256 + threadIdx.x;
  float s = 0.f;
#pragma unroll
  for (int p = 0; p < 16; ++p) s += partial[(size_t)p * (16 * D1_) + idx];
  dz[idx] = s * gp[idx];
}

// ---------------------------------------------------------------------------
// Fused weight updates. grid = 2048:
//   blocks [0,1024):   W0_new — block owns 4 rows (held in regs), all 16 b.
//   blocks [1024,2048): W1_new — block owns 1 row (4 col-chunks in regs).
// Per-b writes are 16 KB contiguous per block; weights read exactly once.
// ---------------------------------------------------------------------------
__global__ __launch_bounds__(256) void update_both(
    const float* __restrict__ W0, const float* __restrict__ dz,
    const float* __restrict__ kt,
    const float* __restrict__ W1, const float* __restrict__ dh,
    const float* __restrict__ g,
    float* __restrict__ out1, float* __restrict__ out2) {
  const int t   = threadIdx.x;
  const int blk = blockIdx.x;
  if (blk < 1024) {
    const int i0 = blk << 2;        // 4 rows of W0
    const int j  = t << 2;          // [0,1024) step 4
    vf4 w[4];
#pragma unroll
    for (int r = 0; r < 4; ++r)
      w[r] = *(const vf4*)(W0 + ((size_t)(i0 + r) << 10) + j);
#pragma unroll
    for (int b = 0; b < 16; ++b) {
      const vf4 k4 = *(const vf4*)(kt + (b << 10) + j);
      float* ob = out1 + ((size_t)b << 22);
#pragma unroll
      for (int r = 0; r < 4; ++r) {
        const float d = LR_ * dz[(b << 12) + i0 + r];
        *(vf4*)(ob + ((size_t)(i0 + r) << 10) + j) = w[r] - d * k4;
      }
    }
  } else {
    const int i = blk - 1024;       // 1 row of W1 (4096 floats)
    vf4 w[4];
#pragma unroll
    for (int c = 0; c < 4; ++c)
      w[c] = *(const vf4*)(W1 + ((size_t)i << 12) + (c << 10) + (t << 2));
#pragma unroll
    for (int b = 0; b < 16; ++b) {
      const float d = LR_ * dh[(b << 10) + i];
      float* ob = out2 + ((size_t)b << 22) + ((size_t)i << 12);
      const float* gb = g + (b << 12);
#pragma unroll
      for (int c = 0; c < 4; ++c) {
        const vf4 g4 = *(const vf4*)(gb + (c << 10) + (t << 2));
        *(vf4*)(ob + (c << 10) + (t << 2)) = w[c] - d * g4;
      }
    }
  }
}

extern "C" void kernel_launch(void* const* d_in, const int* in_sizes, int n_in,
                              void* d_out, int out_size, void* d_ws, size_t ws_size,
                              hipStream_t stream) {
  const float* x_t = (const float*)d_in[0];  // [16,1024]
  const float* W_k = (const float*)d_in[1];  // [1024,1024]
  const float* W_v = (const float*)d_in[2];  // [1024,1024]
  const float* W_o = (const float*)d_in[3];  // [1024,1024]
  const float* W0  = (const float*)d_in[4];  // [4096,1024]
  const float* W1  = (const float*)d_in[5];  // [1024,4096]

  float* out0 = (float*)d_out;               // output [16,1024]
  float* out1 = out0 + 16384;                // W0_new [16,4096,1024]
  float* out2 = out1 + (size_t)16 * 4096 * 1024;  // W1_new [16,1024,4096]

  // workspace layout (floats)
  float* ws      = (float*)d_ws;
  float* kt      = ws;                  // 16*1024
  float* vt      = kt + 16384;          // 16*1024
  float* z       = vt + 16384;          // 16*4096 (unused now, layout kept)
  float* g       = z + 65536;           // 16*4096
  float* gp      = g + 65536;           // 16*4096
  float* h       = gp + 65536;          // 16*1024
  float* dh      = h + 16384;           // 16*1024
  float* dz      = dh + 16384;          // 16*4096
  float* partial = dz + 65536;          // 16*16*4096

  // projections: k_t = x @ W_k^T, v_t = x @ W_v^T  (one dispatch)
  proj_kernel<<<512, 256, 0, stream>>>(W_k, W_v, x_t, kt, vt);
  // forward MLP with fused GELU
  z_gelu_kernel<<<1024, 256, 0, stream>>>(W0, kt, g, gp);
  // h = W1 @ g with fused dh
  h_dh_kernel<<<256, 256, 0, stream>>>(W1, g, vt, h, dh);
  // gradient
  colgemm_partial<<<dim3(16, 16), 256, 0, stream>>>(W1, dh, partial);
  reduce_dz<<<256, 256, 0, stream>>>(partial, gp, dz);
  // output projection: output = h @ W_o^T
  rowgemm16<<<256, 256, 0, stream>>>(W_o, h, out0, 1024, 1024);
  // fused weight updates (the two big streaming writes)
  update_both<<<2048, 256, 0, stream>>>(W0, dz, kt, W1, dh, g, out1, out2);
}